// Round 12
// baseline (1174.235 us; speedup 1.0000x reference)
//
#include <hip/hip_runtime.h>
#include <stdint.h>

#define NB 2
#define NS 2048
#define ND 2048
#define NH 16
#define NHD 128
#define NFF 8192
#define NBS (NB*NS)   // 4096 rows
#define NQKV 2304     // 2048 q + 256 kv

typedef unsigned short u16;
typedef __attribute__((ext_vector_type(8))) short bf16x8;   // 8 bf16 = 4 VGPRs
typedef __attribute__((ext_vector_type(4))) unsigned short u16x4;
typedef __attribute__((ext_vector_type(4))) float f32x4;

__device__ __forceinline__ u16 f2bf(float f) {
  union { float f; unsigned u; } v; v.f = f;
  unsigned r = v.u + 0x7fffu + ((v.u >> 16) & 1u);   // RNE
  return (u16)(r >> 16);
}
__device__ __forceinline__ float bf2f(u16 h) {
  union { unsigned u; float f; } v; v.u = ((unsigned)h) << 16;
  return v.f;
}
__device__ __forceinline__ void async_cp16(const void* g, void* l) {
  __builtin_amdgcn_global_load_lds((const __attribute__((address_space(1))) void*)g,
                                   (__attribute__((address_space(3))) void*)l, 16, 0, 0);
}

// ---------------- fp32 -> bf16 ----------------
__global__ void cvt_bf16_kernel(const float* __restrict__ in, u16* __restrict__ out, int n4) {
  int i = blockIdx.x * blockDim.x + threadIdx.x;
  if (i >= n4) return;
  float4 v = reinterpret_cast<const float4*>(in)[i];
  u16x4 o; o.x = f2bf(v.x); o.y = f2bf(v.y); o.z = f2bf(v.z); o.w = f2bf(v.w);
  reinterpret_cast<u16x4*>(out)[i] = o;
}

// ---------------- RMSNorm (fp32 in -> bf16 out), one block per row ----------------
__global__ __launch_bounds__(256) void rmsnorm_kernel(const float* __restrict__ x,
                                                      const float* __restrict__ w,
                                                      u16* __restrict__ out) {
  const int row = blockIdx.x, tid = threadIdx.x;
  const float* xr = x + (size_t)row * ND;
  float4 a = *reinterpret_cast<const float4*>(xr + tid * 8);
  float4 b = *reinterpret_cast<const float4*>(xr + tid * 8 + 4);
  float ss = a.x*a.x + a.y*a.y + a.z*a.z + a.w*a.w
           + b.x*b.x + b.y*b.y + b.z*b.z + b.w*b.w;
#pragma unroll
  for (int off = 32; off > 0; off >>= 1) ss += __shfl_down(ss, off);
  __shared__ float red[4];
  __shared__ float rinv_s;
  if ((tid & 63) == 0) red[tid >> 6] = ss;
  __syncthreads();
  if (tid == 0) rinv_s = rsqrtf((red[0] + red[1] + red[2] + red[3]) * (1.0f / ND) + 1e-6f);
  __syncthreads();
  const float rinv = rinv_s;
  const float* wr = w + tid * 8;
  u16* orow = out + (size_t)row * ND + tid * 8;
  float vs[8] = {a.x, a.y, a.z, a.w, b.x, b.y, b.z, b.w};
#pragma unroll
  for (int j = 0; j < 8; ++j) orow[j] = f2bf(vs[j] * rinv * wr[j]);
}

// ---------------- RoPE cos/sin table [S][64] ----------------
__global__ void rope_table_kernel(float* __restrict__ cosT, float* __restrict__ sinT) {
  int i = blockIdx.x * blockDim.x + threadIdx.x;
  if (i >= NS * 64) return;
  int s = i >> 6, d = i & 63;
  float freq = expf(-(float)d * (9.210340371976184f / 64.0f));  // 10000^(-d/64)
  float ang = (float)s * freq;
  cosT[i] = cosf(ang);
  sinT[i] = sinf(ang);
}

// ---- RoPE for Q: qkvraw [B,S,2304] bf16 -> [B*H, S, HD] bf16, pre-scaled 1/sqrt(HD) ----
__global__ void rope_q_kernel(const u16* __restrict__ qkvraw, const float* __restrict__ cosT,
                              const float* __restrict__ sinT, u16* __restrict__ qout) {
  int i = blockIdx.x * blockDim.x + threadIdx.x;
  if (i >= NB * NS * NH * 64) return;
  int d = i & 63, h = (i >> 6) & 15, s = (i >> 10) & (NS - 1), b = i >> 21;
  size_t rrow = ((size_t)(b * NS + s)) * NQKV + h * NHD;
  float t1 = bf2f(qkvraw[rrow + d]);
  float t2 = bf2f(qkvraw[rrow + d + 64]);
  float c = cosT[(s << 6) + d], sn = sinT[(s << 6) + d];
  const float scale = 0.08838834764831845f;  // 1/sqrt(128)
  size_t orow = (((size_t)(b * NH + h)) * NS + s) * NHD;
  qout[orow + d]      = f2bf((t1 * c - t2 * sn) * scale);
  qout[orow + d + 64] = f2bf((t2 * c + t1 * sn) * scale);
}

// ---- RoPE for K + transpose-copy V: qkvraw[...,2048+] -> k [B,S,HD], vt [B,128,S] ----
__global__ void rope_kv_kernel(const u16* __restrict__ qkvraw, const float* __restrict__ cosT,
                               const float* __restrict__ sinT, u16* __restrict__ kout,
                               u16* __restrict__ vtout) {
  int i = blockIdx.x * blockDim.x + threadIdx.x;
  if (i >= NB * NS * 64) return;
  int d = i & 63, s = (i >> 6) & (NS - 1), b = i >> 17;
  size_t rrow = ((size_t)(b * NS + s)) * NQKV + ND;
  float t1 = bf2f(qkvraw[rrow + d]);
  float t2 = bf2f(qkvraw[rrow + d + 64]);
  float c = cosT[(s << 6) + d], sn = sinT[(s << 6) + d];
  size_t orow = ((size_t)(b * NS + s)) * NHD;
  kout[orow + d]      = f2bf(t1 * c - t2 * sn);
  kout[orow + d + 64] = f2bf(t2 * c + t1 * sn);
  vtout[((size_t)(b * 128 + d)) * NS + s]      = qkvraw[rrow + 128 + d];
  vtout[((size_t)(b * 128 + d + 64)) * NS + s] = qkvraw[rrow + 128 + d + 64];
}

// ---------------- GEMM v9 (m97-structure + swizzle): C = A[M,K] @ W[N,K]^T (bf16) ----------------
// 128x128 tile, BK=64, 4 waves (2x2), 256 threads. SINGLE-buffered 32KB LDS ->
// multiple blocks/CU resident; cross-BLOCK overlap hides the per-tile barrier drain.
// T2 swizzle (pre-swizzled global source, linear LDS dest, swizzled reads) -> 0 conflicts.
template <int EPI>
__global__ __launch_bounds__(256) void gemm3_kernel(const u16* __restrict__ A,
                                                    const u16* __restrict__ W,
                                                    void* Out, const void* Aux,
                                                    int M, int N, int K) {
  __shared__ __align__(16) char As[128 * 128];   // 128 rows x 128B
  __shared__ __align__(16) char Bs[128 * 128];
  const int tid = threadIdx.x, wave = tid >> 6, lane = tid & 63;
  const int lm = lane & 15, lg = lane >> 4;

  int bx, by;
  {
    const int gx = gridDim.x;
    if ((gx & 7) == 0) {
      const int id = blockIdx.y * gx + blockIdx.x;
      const int xcd = id & 7, rank = id >> 3;
      const int cw = gx >> 3;
      bx = xcd * cw + rank % cw;
      by = rank / cw;
    } else { bx = blockIdx.x; by = blockIdx.y; }
  }
  const int m0 = by * 128, n0 = bx * 128;
  const int wr = wave >> 1, wc = wave & 1;

  f32x4 acc[4][4];
#pragma unroll
  for (int i = 0; i < 4; ++i)
#pragma unroll
    for (int j = 0; j < 4; ++j) acc[i][j] = (f32x4){0.f, 0.f, 0.f, 0.f};

  for (int k0 = 0; k0 < K; k0 += 64) {
#pragma unroll
    for (int p = 0; p < 4; ++p) {
      int X = p * 4096 + tid * 16;            // byte offset within 16KB tile
      int r = X >> 7;                         // row (128B rows)
      int sw = ((X >> 4) ^ (X >> 7)) & 7;     // source 16B group
      async_cp16(A + (size_t)(m0 + r) * K + k0 + sw * 8, As + p * 4096 + wave * 1024);
      async_cp16(W + (size_t)(n0 + r) * K + k0 + sw * 8, Bs + p * 4096 + wave * 1024);
    }
    __syncthreads();
#pragma unroll
    for (int ks = 0; ks < 2; ++ks) {
      bf16x8 a[4], b[4];
#pragma unroll
      for (int i = 0; i < 4; ++i) {
        const int ra = wr * 64 + i * 16 + lm;
        const int sa = (ks * 4 + lg) ^ (ra & 7);
        a[i] = *(const bf16x8*)(As + ra * 128 + sa * 16);
        const int rb = wc * 64 + i * 16 + lm;
        const int sb = (ks * 4 + lg) ^ (rb & 7);
        b[i] = *(const bf16x8*)(Bs + rb * 128 + sb * 16);
      }
#pragma unroll
      for (int i = 0; i < 4; ++i)
#pragma unroll
        for (int j = 0; j < 4; ++j)
          acc[i][j] = __builtin_amdgcn_mfma_f32_16x16x32_bf16(a[i], b[j], acc[i][j], 0, 0, 0);
    }
    __syncthreads();
  }

#pragma unroll
  for (int i = 0; i < 4; ++i) {
    const int row_b = m0 + wr * 64 + i * 16 + lg * 4;
#pragma unroll
    for (int j = 0; j < 4; ++j) {
      const int col = n0 + wc * 64 + j * 16 + lm;
#pragma unroll
      for (int r = 0; r < 4; ++r) {
        size_t idx = (size_t)(row_b + r) * N + col;
        float v = acc[i][j][r];
        if constexpr (EPI == 0) {
          ((u16*)Out)[idx] = f2bf(v);
        } else if constexpr (EPI == 1) {
          ((float*)Out)[idx] = v + ((const float*)Aux)[idx];
        } else {
          float a1 = bf2f(((const u16*)Aux)[idx]);
          float s = a1 / (1.0f + expf(-a1));   // silu
          ((u16*)Out)[idx] = f2bf(s * v);
        }
      }
    }
  }
}

// ---------------- Flash attention v2: TLP design, no staging, no barriers ----------------
// grid (S/16, B*H), 64 threads = 1 wave; wave owns 16 q rows; KV tiles of 64.
// K and V^T fragments load DIRECTLY global->register (K/V total 2MB = L2-resident).
// P transpose via wave-private 2.3KB LDS (no __syncthreads anywhere).
__global__ __launch_bounds__(64, 4) void attn_kernel(const u16* __restrict__ q,
                                                     const u16* __restrict__ kg,
                                                     const u16* __restrict__ vt,
                                                     u16* __restrict__ out) {
  __shared__ __align__(16) u16 Plds[16 * 72];
  const int lane = threadIdx.x & 63;
  const int q16 = (gridDim.x - 1) - blockIdx.x;   // heavy blocks first
  const int bh = blockIdx.y, b = bh >> 4, h = bh & 15;
  const float slope = exp2f(-0.5f * (float)(h + 1));
  const int lm = lane & 15, lg = lane >> 4;
  const int crow = lg * 4;
  const int qrow0 = q16 * 16;

  // Q A-fragments (q pre-scaled by 1/sqrt(HD))
  bf16x8 qf[4];
  {
    const u16* qbase = q + ((size_t)bh * NS + qrow0 + lm) * NHD + lg * 8;
#pragma unroll
    for (int kc = 0; kc < 4; ++kc) qf[kc] = *(const bf16x8*)(qbase + kc * 32);
  }

  float Mr[4], Lr[4];
  f32x4 O[8];
#pragma unroll
  for (int r = 0; r < 4; ++r) { Mr[r] = -__builtin_inff(); Lr[r] = 0.f; }
#pragma unroll
  for (int t = 0; t < 8; ++t) O[t] = (f32x4){0.f, 0.f, 0.f, 0.f};

  const u16* kbase = kg + (size_t)b * NS * NHD;   // [s][128]
  const u16* vbase = vt + (size_t)b * 128 * NS;   // [d][s]

  const int ntiles = q16 / 4 + 1;
  for (int t0 = 0; t0 < ntiles; ++t0) {
    const int kv0 = t0 * 64;

    // ---- QK^T: K frags direct from global (L2-hot) ----
    f32x4 sc[4];
#pragma unroll
    for (int sub = 0; sub < 4; ++sub) sc[sub] = (f32x4){0.f, 0.f, 0.f, 0.f};
#pragma unroll
    for (int sub = 0; sub < 4; ++sub) {
      const u16* kr = kbase + (size_t)(kv0 + sub * 16 + lm) * NHD + lg * 8;
#pragma unroll
      for (int kc = 0; kc < 4; ++kc) {
        bf16x8 kf = *(const bf16x8*)(kr + kc * 32);
        sc[sub] = __builtin_amdgcn_mfma_f32_16x16x32_bf16(qf[kc], kf, sc[sub], 0, 0, 0);
      }
    }

    // ---- ALiBi + causal + online softmax (row = 16-lane group) ----
    float esc[4], pp[4][4];
#pragma unroll
    for (int r = 0; r < 4; ++r) {
      const int sq = qrow0 + crow + r;
      float v[4];
#pragma unroll
      for (int sub = 0; sub < 4; ++sub) {
        const int kc_ = kv0 + sub * 16 + lm;
        v[sub] = (kc_ <= sq) ? sc[sub][r] - slope * (float)(sq - kc_) : -1e9f;
      }
      float mx = fmaxf(fmaxf(v[0], v[1]), fmaxf(v[2], v[3]));
      mx = fmaxf(mx, __shfl_xor(mx, 1));
      mx = fmaxf(mx, __shfl_xor(mx, 2));
      mx = fmaxf(mx, __shfl_xor(mx, 4));
      mx = fmaxf(mx, __shfl_xor(mx, 8));
      const float newM = fmaxf(Mr[r], mx);
      esc[r] = __expf(Mr[r] - newM);
      float rs = 0.f;
#pragma unroll
      for (int sub = 0; sub < 4; ++sub) { pp[sub][r] = __expf(v[sub] - newM); rs += pp[sub][r]; }
      rs += __shfl_xor(rs, 1);
      rs += __shfl_xor(rs, 2);
      rs += __shfl_xor(rs, 4);
      rs += __shfl_xor(rs, 8);
      Lr[r] = Lr[r] * esc[r] + rs;
      Mr[r] = newM;
    }
#pragma unroll
    for (int t = 0; t < 8; ++t) {
      O[t][0] *= esc[0]; O[t][1] *= esc[1]; O[t][2] *= esc[2]; O[t][3] *= esc[3];
    }

    // ---- P -> wave-private LDS (transpose); no barrier: single wave ----
#pragma unroll
    for (int sub = 0; sub < 4; ++sub)
#pragma unroll
      for (int r = 0; r < 4; ++r)
        Plds[(crow + r) * 72 + sub * 16 + lm] = f2bf(pp[sub][r]);

    bf16x8 pa0 = *(const bf16x8*)&Plds[lm * 72 + lg * 8];
    bf16x8 pa1 = *(const bf16x8*)&Plds[lm * 72 + 32 + lg * 8];

    // ---- PV: V^T frags direct from global (L2-hot) ----
#pragma unroll
    for (int dt = 0; dt < 8; ++dt) {
      const u16* vr = vbase + (size_t)(dt * 16 + lm) * NS + kv0 + lg * 8;
      bf16x8 vf0 = *(const bf16x8*)(vr);
      bf16x8 vf1 = *(const bf16x8*)(vr + 32);
      O[dt] = __builtin_amdgcn_mfma_f32_16x16x32_bf16(pa0, vf0, O[dt], 0, 0, 0);
      O[dt] = __builtin_amdgcn_mfma_f32_16x16x32_bf16(pa1, vf1, O[dt], 0, 0, 0);
    }
  }

  // ---- normalize + store [B,S,H*HD] ----
#pragma unroll
  for (int dt = 0; dt < 8; ++dt) {
#pragma unroll
    for (int r = 0; r < 4; ++r) {
      const int sq = qrow0 + crow + r;
      out[((size_t)b * NS + sq) * ND + h * NHD + dt * 16 + lm] = f2bf(O[dt][r] / Lr[r]);
    }
  }
}

// ---------------- host ----------------
extern "C" void kernel_launch(void* const* d_in, const int* in_sizes, int n_in,
                              void* d_out, int out_size, void* d_ws, size_t ws_size,
                              hipStream_t stream) {
  const float* x   = (const float*)d_in[0];
  const float* wn1 = (const float*)d_in[2];
  const float* wn2 = (const float*)d_in[3];
  const float* qw  = (const float*)d_in[4];
  const float* kvw = (const float*)d_in[5];
  const float* ow  = (const float*)d_in[6];
  const float* w1  = (const float*)d_in[7];
  const float* w2  = (const float*)d_in[8];
  const float* w3  = (const float*)d_in[9];
  float* out = (float*)d_out;

  const size_t MiB = 1024 * 1024;
  const size_t NEED = 161 * MiB;
  if (ws_size < NEED) return;

  char* ws = (char*)d_ws;
  u16*   R_W    = (u16*)(ws);
  u16*   QKVRAW = (u16*)(ws + 48 * MiB);
  u16*   AO     = QKVRAW;
  u16*   A1     = (u16*)(ws + 48 * MiB);
  u16*   QB     = (u16*)(ws + 112 * MiB);
  u16*   KB     = (u16*)(ws + 128 * MiB);
  u16*   VT     = (u16*)(ws + 129 * MiB);
  float* X2     = (float*)(ws + 112 * MiB);
  u16*   Hbf    = (u16*)(ws + 144 * MiB);
  float* COS    = (float*)(ws + 160 * MiB);
  float* SIN    = (float*)(ws + 160 * MiB + 512 * 1024);

  auto cvt = [&](const float* src, u16* dst, size_t n) {
    int n4 = (int)(n / 4);
    cvt_bf16_kernel<<<(n4 + 255) / 256, 256, 0, stream>>>(src, dst, n4);
  };

  rope_table_kernel<<<(NS * 64 + 255) / 256, 256, 0, stream>>>(COS, SIN);

  // h = rmsnorm(x, wn1)
  rmsnorm_kernel<<<NBS, 256, 0, stream>>>(x, wn1, Hbf);

  // qkv_raw = h @ [qw; kvw]^T   (fused, N=2304)
  cvt(qw, R_W, (size_t)ND * ND);
  cvt(kvw, R_W + (size_t)ND * ND, (size_t)256 * ND);
  gemm3_kernel<0><<<dim3(NQKV / 128, NBS / 128), 256, 0, stream>>>(
      Hbf, R_W, (void*)QKVRAW, nullptr, NBS, NQKV, ND);

  // rope
  rope_q_kernel<<<(NB * NS * NH * 64) / 256, 256, 0, stream>>>(QKVRAW, COS, SIN, QB);
  rope_kv_kernel<<<(NB * NS * 64) / 256, 256, 0, stream>>>(QKVRAW, COS, SIN, KB, VT);

  // attention -> AO   (1 wave per 16 q-rows; K/V direct from L2)
  attn_kernel<<<dim3(NS / 16, NB * NH), 64, 0, stream>>>(QB, KB, VT, AO);

  // x2 = x + ao @ ow^T
  cvt(ow, R_W, (size_t)ND * ND);
  gemm3_kernel<1><<<dim3(ND / 128, NBS / 128), 256, 0, stream>>>(
      AO, R_W, (void*)X2, (const void*)x, NBS, ND, ND);

  // h2 = rmsnorm(x2, wn2)
  rmsnorm_kernel<<<NBS, 256, 0, stream>>>(X2, wn2, Hbf);

  // a1 = h2 @ w1^T
  cvt(w1, R_W, (size_t)NFF * ND);
  gemm3_kernel<0><<<dim3(NFF / 128, NBS / 128), 256, 0, stream>>>(
      Hbf, R_W, (void*)A1, nullptr, NBS, NFF, ND);
  // g = silu(a1) * (h2 @ w2^T)  (in-place over A1)
  cvt(w2, R_W, (size_t)NFF * ND);
  gemm3_kernel<2><<<dim3(NFF / 128, NBS / 128), 256, 0, stream>>>(
      Hbf, R_W, (void*)A1, (const void*)A1, NBS, NFF, ND);

  // out = x2 + g @ w3^T
  cvt(w3, R_W, (size_t)ND * NFF);
  gemm3_kernel<1><<<dim3(ND / 128, NBS / 128), 256, 0, stream>>>(
      A1, R_W, (void*)out, (const void*)X2, NBS, ND, NFF);
}

// Round 13
// 1009.800 us; speedup vs baseline: 1.1628x; 1.1628x over previous
//
#include <hip/hip_runtime.h>
#include <stdint.h>

#define NB 2
#define NS 2048
#define ND 2048
#define NH 16
#define NHD 128
#define NFF 8192
#define NBS (NB*NS)   // 4096 rows
#define NQKV 2304     // 2048 q + 256 kv

typedef unsigned short u16;
typedef __attribute__((ext_vector_type(8))) short bf16x8;   // 8 bf16 = 4 VGPRs
typedef __attribute__((ext_vector_type(4))) unsigned short u16x4;
typedef __attribute__((ext_vector_type(4))) float f32x4;

__device__ __forceinline__ u16 f2bf(float f) {
  union { float f; unsigned u; } v; v.f = f;
  unsigned r = v.u + 0x7fffu + ((v.u >> 16) & 1u);   // RNE
  return (u16)(r >> 16);
}
__device__ __forceinline__ float bf2f(u16 h) {
  union { unsigned u; float f; } v; v.u = ((unsigned)h) << 16;
  return v.f;
}
__device__ __forceinline__ void async_cp16(const void* g, void* l) {
  __builtin_amdgcn_global_load_lds((const __attribute__((address_space(1))) void*)g,
                                   (__attribute__((address_space(3))) void*)l, 16, 0, 0);
}

// ---------------- fp32 -> bf16 ----------------
__global__ void cvt_bf16_kernel(const float* __restrict__ in, u16* __restrict__ out, int n4) {
  int i = blockIdx.x * blockDim.x + threadIdx.x;
  if (i >= n4) return;
  float4 v = reinterpret_cast<const float4*>(in)[i];
  u16x4 o; o.x = f2bf(v.x); o.y = f2bf(v.y); o.z = f2bf(v.z); o.w = f2bf(v.w);
  reinterpret_cast<u16x4*>(out)[i] = o;
}

// ---------------- RMSNorm (fp32 in -> bf16 out), one block per row ----------------
__global__ __launch_bounds__(256) void rmsnorm_kernel(const float* __restrict__ x,
                                                      const float* __restrict__ w,
                                                      u16* __restrict__ out) {
  const int row = blockIdx.x, tid = threadIdx.x;
  const float* xr = x + (size_t)row * ND;
  float4 a = *reinterpret_cast<const float4*>(xr + tid * 8);
  float4 b = *reinterpret_cast<const float4*>(xr + tid * 8 + 4);
  float ss = a.x*a.x + a.y*a.y + a.z*a.z + a.w*a.w
           + b.x*b.x + b.y*b.y + b.z*b.z + b.w*b.w;
#pragma unroll
  for (int off = 32; off > 0; off >>= 1) ss += __shfl_down(ss, off);
  __shared__ float red[4];
  __shared__ float rinv_s;
  if ((tid & 63) == 0) red[tid >> 6] = ss;
  __syncthreads();
  if (tid == 0) rinv_s = rsqrtf((red[0] + red[1] + red[2] + red[3]) * (1.0f / ND) + 1e-6f);
  __syncthreads();
  const float rinv = rinv_s;
  const float* wr = w + tid * 8;
  u16* orow = out + (size_t)row * ND + tid * 8;
  float vs[8] = {a.x, a.y, a.z, a.w, b.x, b.y, b.z, b.w};
#pragma unroll
  for (int j = 0; j < 8; ++j) orow[j] = f2bf(vs[j] * rinv * wr[j]);
}

// ---------------- RoPE cos/sin table [S][64] ----------------
__global__ void rope_table_kernel(float* __restrict__ cosT, float* __restrict__ sinT) {
  int i = blockIdx.x * blockDim.x + threadIdx.x;
  if (i >= NS * 64) return;
  int s = i >> 6, d = i & 63;
  float freq = expf(-(float)d * (9.210340371976184f / 64.0f));  // 10000^(-d/64)
  float ang = (float)s * freq;
  cosT[i] = cosf(ang);
  sinT[i] = sinf(ang);
}

// ---- RoPE for Q: qkvraw [B,S,2304] bf16 -> [B*H, S, HD] bf16, pre-scaled 1/sqrt(HD) ----
__global__ void rope_q_kernel(const u16* __restrict__ qkvraw, const float* __restrict__ cosT,
                              const float* __restrict__ sinT, u16* __restrict__ qout) {
  int i = blockIdx.x * blockDim.x + threadIdx.x;
  if (i >= NB * NS * NH * 64) return;
  int d = i & 63, h = (i >> 6) & 15, s = (i >> 10) & (NS - 1), b = i >> 21;
  size_t rrow = ((size_t)(b * NS + s)) * NQKV + h * NHD;
  float t1 = bf2f(qkvraw[rrow + d]);
  float t2 = bf2f(qkvraw[rrow + d + 64]);
  float c = cosT[(s << 6) + d], sn = sinT[(s << 6) + d];
  const float scale = 0.08838834764831845f;  // 1/sqrt(128)
  size_t orow = (((size_t)(b * NH + h)) * NS + s) * NHD;
  qout[orow + d]      = f2bf((t1 * c - t2 * sn) * scale);
  qout[orow + d + 64] = f2bf((t2 * c + t1 * sn) * scale);
}

// ---- RoPE for K + transpose-copy V: qkvraw[...,2048+] -> k [B,S,HD], vt [B,128,S] ----
__global__ void rope_kv_kernel(const u16* __restrict__ qkvraw, const float* __restrict__ cosT,
                               const float* __restrict__ sinT, u16* __restrict__ kout,
                               u16* __restrict__ vtout) {
  int i = blockIdx.x * blockDim.x + threadIdx.x;
  if (i >= NB * NS * 64) return;
  int d = i & 63, s = (i >> 6) & (NS - 1), b = i >> 17;
  size_t rrow = ((size_t)(b * NS + s)) * NQKV + ND;
  float t1 = bf2f(qkvraw[rrow + d]);
  float t2 = bf2f(qkvraw[rrow + d + 64]);
  float c = cosT[(s << 6) + d], sn = sinT[(s << 6) + d];
  size_t orow = ((size_t)(b * NS + s)) * NHD;
  kout[orow + d]      = f2bf(t1 * c - t2 * sn);
  kout[orow + d + 64] = f2bf(t2 * c + t1 * sn);
  vtout[((size_t)(b * 128 + d)) * NS + s]      = qkvraw[rrow + 128 + d];
  vtout[((size_t)(b * 128 + d + 64)) * NS + s] = qkvraw[rrow + 128 + d + 64];
}

// ---------------- GEMM v9 (m97-structure + swizzle): C = A[M,K] @ W[N,K]^T (bf16) ----------------
// 128x128 tile, BK=64, 4 waves (2x2), 256 threads. SINGLE-buffered 32KB LDS ->
// multiple blocks/CU resident; cross-BLOCK overlap hides the per-tile barrier drain.
// T2 swizzle (pre-swizzled global source, linear LDS dest, swizzled reads) -> 0 conflicts.
template <int EPI>
__global__ __launch_bounds__(256) void gemm3_kernel(const u16* __restrict__ A,
                                                    const u16* __restrict__ W,
                                                    void* Out, const void* Aux,
                                                    int M, int N, int K) {
  __shared__ __align__(16) char As[128 * 128];   // 128 rows x 128B
  __shared__ __align__(16) char Bs[128 * 128];
  const int tid = threadIdx.x, wave = tid >> 6, lane = tid & 63;
  const int lm = lane & 15, lg = lane >> 4;

  int bx, by;
  {
    const int gx = gridDim.x;
    if ((gx & 7) == 0) {
      const int id = blockIdx.y * gx + blockIdx.x;
      const int xcd = id & 7, rank = id >> 3;
      const int cw = gx >> 3;
      bx = xcd * cw + rank % cw;
      by = rank / cw;
    } else { bx = blockIdx.x; by = blockIdx.y; }
  }
  const int m0 = by * 128, n0 = bx * 128;
  const int wr = wave >> 1, wc = wave & 1;

  f32x4 acc[4][4];
#pragma unroll
  for (int i = 0; i < 4; ++i)
#pragma unroll
    for (int j = 0; j < 4; ++j) acc[i][j] = (f32x4){0.f, 0.f, 0.f, 0.f};

  for (int k0 = 0; k0 < K; k0 += 64) {
#pragma unroll
    for (int p = 0; p < 4; ++p) {
      int X = p * 4096 + tid * 16;            // byte offset within 16KB tile
      int r = X >> 7;                         // row (128B rows)
      int sw = ((X >> 4) ^ (X >> 7)) & 7;     // source 16B group
      async_cp16(A + (size_t)(m0 + r) * K + k0 + sw * 8, As + p * 4096 + wave * 1024);
      async_cp16(W + (size_t)(n0 + r) * K + k0 + sw * 8, Bs + p * 4096 + wave * 1024);
    }
    __syncthreads();
#pragma unroll
    for (int ks = 0; ks < 2; ++ks) {
      bf16x8 a[4], b[4];
#pragma unroll
      for (int i = 0; i < 4; ++i) {
        const int ra = wr * 64 + i * 16 + lm;
        const int sa = (ks * 4 + lg) ^ (ra & 7);
        a[i] = *(const bf16x8*)(As + ra * 128 + sa * 16);
        const int rb = wc * 64 + i * 16 + lm;
        const int sb = (ks * 4 + lg) ^ (rb & 7);
        b[i] = *(const bf16x8*)(Bs + rb * 128 + sb * 16);
      }
#pragma unroll
      for (int i = 0; i < 4; ++i)
#pragma unroll
        for (int j = 0; j < 4; ++j)
          acc[i][j] = __builtin_amdgcn_mfma_f32_16x16x32_bf16(a[i], b[j], acc[i][j], 0, 0, 0);
    }
    __syncthreads();
  }

#pragma unroll
  for (int i = 0; i < 4; ++i) {
    const int row_b = m0 + wr * 64 + i * 16 + lg * 4;
#pragma unroll
    for (int j = 0; j < 4; ++j) {
      const int col = n0 + wc * 64 + j * 16 + lm;
#pragma unroll
      for (int r = 0; r < 4; ++r) {
        size_t idx = (size_t)(row_b + r) * N + col;
        float v = acc[i][j][r];
        if constexpr (EPI == 0) {
          ((u16*)Out)[idx] = f2bf(v);
        } else if constexpr (EPI == 1) {
          ((float*)Out)[idx] = v + ((const float*)Aux)[idx];
        } else {
          float a1 = bf2f(((const u16*)Aux)[idx]);
          float s = a1 / (1.0f + expf(-a1));   // silu
          ((u16*)Out)[idx] = f2bf(s * v);
        }
      }
    }
  }
}

// ---------------- Flash attention v3: staged K, direct-L2 V ----------------
// grid (S/64, B*H), 256 threads = 4 waves; wave = 16 q rows; KV tiles of 64.
// K staged in LDS (swizzled source, conflict-free reads); V^T read DIRECTLY from
// global (L2-resident, 1MB/batch) inside PV — no V staging, no vmcnt drain for V.
// LDS 25KB -> 6 blocks/CU (24 waves) for cross-block latency hiding.
__global__ __launch_bounds__(256) void attn_kernel(const u16* __restrict__ q,
                                                   const u16* __restrict__ kg,
                                                   const u16* __restrict__ vt,
                                                   u16* __restrict__ out) {
  __shared__ __align__(16) u16 Klds[64 * 128];   // 16KB
  __shared__ __align__(16) u16 Plds[4][16 * 72]; // 9KB, wave-private
  const int tid = threadIdx.x, wave = tid >> 6, lane = tid & 63;
  const int qt = (gridDim.x - 1) - blockIdx.x;   // heavy blocks first
  const int q0 = qt * 64;
  const int bh = blockIdx.y, b = bh >> 4, h = bh & 15;
  const float slope = exp2f(-0.5f * (float)(h + 1));
  const int lm = lane & 15, lg = lane >> 4;
  const int crow = lg * 4;

  bf16x8 qf[4];
  {
    const int qrow = q0 + wave * 16 + lm;
    const u16* qbase = q + ((size_t)bh * NS + qrow) * NHD + lg * 8;
#pragma unroll
    for (int kc = 0; kc < 4; ++kc) qf[kc] = *(const bf16x8*)(qbase + kc * 32);
  }

  float Mr[4], Lr[4];
  f32x4 O[8];
#pragma unroll
  for (int r = 0; r < 4; ++r) { Mr[r] = -__builtin_inff(); Lr[r] = 0.f; }
#pragma unroll
  for (int t = 0; t < 8; ++t) O[t] = (f32x4){0.f, 0.f, 0.f, 0.f};

  const int kslotK = tid & 15;
  const int kvK    = tid >> 4;
  u16* pw = Plds[wave];
  const u16* vbase = vt + (size_t)b * 128 * NS;   // [d][s], L2-hot

  const int ntiles = qt + 1;
  for (int t0 = 0; t0 < ntiles; ++t0) {
    const int kv0 = t0 * 64;
    __syncthreads();   // prior-iter K reads done before overwrite
#pragma unroll
    for (int p = 0; p < 4; ++p) {
      int kv = p * 16 + kvK;
      const u16* src = kg + ((size_t)b * NS + kv0 + kv) * NHD + ((kslotK ^ (kv & 7)) * 8);
      async_cp16(src, (char*)Klds + p * 4096 + wave * 1024);
    }
    __syncthreads();   // staged K visible

    // ---- QK^T from LDS ----
    f32x4 sc[4];
#pragma unroll
    for (int sub = 0; sub < 4; ++sub) sc[sub] = (f32x4){0.f, 0.f, 0.f, 0.f};
#pragma unroll
    for (int sub = 0; sub < 4; ++sub) {
      const int kv = sub * 16 + lm;
#pragma unroll
      for (int kc = 0; kc < 4; ++kc) {
        const int slot = (kc * 4 + lg) ^ (kv & 7);
        bf16x8 kf = *(const bf16x8*)((const char*)Klds + kv * 256 + slot * 16);
        sc[sub] = __builtin_amdgcn_mfma_f32_16x16x32_bf16(qf[kc], kf, sc[sub], 0, 0, 0);
      }
    }

    // ---- ALiBi + causal + online softmax ----
    float esc[4], pp[4][4];
#pragma unroll
    for (int r = 0; r < 4; ++r) {
      const int sq = q0 + wave * 16 + crow + r;
      float v[4];
#pragma unroll
      for (int sub = 0; sub < 4; ++sub) {
        const int kc_ = kv0 + sub * 16 + lm;
        v[sub] = (kc_ <= sq) ? sc[sub][r] - slope * (float)(sq - kc_) : -1e9f;
      }
      float mx = fmaxf(fmaxf(v[0], v[1]), fmaxf(v[2], v[3]));
      mx = fmaxf(mx, __shfl_xor(mx, 1));
      mx = fmaxf(mx, __shfl_xor(mx, 2));
      mx = fmaxf(mx, __shfl_xor(mx, 4));
      mx = fmaxf(mx, __shfl_xor(mx, 8));
      const float newM = fmaxf(Mr[r], mx);
      esc[r] = __expf(Mr[r] - newM);
      float rs = 0.f;
#pragma unroll
      for (int sub = 0; sub < 4; ++sub) { pp[sub][r] = __expf(v[sub] - newM); rs += pp[sub][r]; }
      rs += __shfl_xor(rs, 1);
      rs += __shfl_xor(rs, 2);
      rs += __shfl_xor(rs, 4);
      rs += __shfl_xor(rs, 8);
      Lr[r] = Lr[r] * esc[r] + rs;
      Mr[r] = newM;
    }
#pragma unroll
    for (int t = 0; t < 8; ++t) {
      O[t][0] *= esc[0]; O[t][1] *= esc[1]; O[t][2] *= esc[2]; O[t][3] *= esc[3];
    }

    // ---- P -> wave-private LDS (padded rows); no cross-wave barrier needed ----
#pragma unroll
    for (int sub = 0; sub < 4; ++sub)
#pragma unroll
      for (int r = 0; r < 4; ++r)
        pw[(crow + r) * 72 + sub * 16 + lm] = f2bf(pp[sub][r]);

    bf16x8 pa0 = *(const bf16x8*)&pw[lm * 72 + lg * 8];
    bf16x8 pa1 = *(const bf16x8*)&pw[lm * 72 + 32 + lg * 8];

    // ---- PV: V^T frags direct from global (L2-hot, no staging) ----
#pragma unroll
    for (int dt = 0; dt < 8; ++dt) {
      const u16* vr = vbase + (size_t)(dt * 16 + lm) * NS + kv0 + lg * 8;
      bf16x8 vf0 = *(const bf16x8*)(vr);
      bf16x8 vf1 = *(const bf16x8*)(vr + 32);
      O[dt] = __builtin_amdgcn_mfma_f32_16x16x32_bf16(pa0, vf0, O[dt], 0, 0, 0);
      O[dt] = __builtin_amdgcn_mfma_f32_16x16x32_bf16(pa1, vf1, O[dt], 0, 0, 0);
    }
  }

  // ---- normalize + store [B,S,H*HD] ----
#pragma unroll
  for (int dt = 0; dt < 8; ++dt) {
#pragma unroll
    for (int r = 0; r < 4; ++r) {
      const int sq = q0 + wave * 16 + crow + r;
      out[((size_t)b * NS + sq) * ND + h * NHD + dt * 16 + lm] = f2bf(O[dt][r] / Lr[r]);
    }
  }
}

// ---------------- host ----------------
extern "C" void kernel_launch(void* const* d_in, const int* in_sizes, int n_in,
                              void* d_out, int out_size, void* d_ws, size_t ws_size,
                              hipStream_t stream) {
  const float* x   = (const float*)d_in[0];
  const float* wn1 = (const float*)d_in[2];
  const float* wn2 = (const float*)d_in[3];
  const float* qw  = (const float*)d_in[4];
  const float* kvw = (const float*)d_in[5];
  const float* ow  = (const float*)d_in[6];
  const float* w1  = (const float*)d_in[7];
  const float* w2  = (const float*)d_in[8];
  const float* w3  = (const float*)d_in[9];
  float* out = (float*)d_out;

  const size_t MiB = 1024 * 1024;
  const size_t NEED = 161 * MiB;
  if (ws_size < NEED) return;

  char* ws = (char*)d_ws;
  u16*   R_W    = (u16*)(ws);
  u16*   QKVRAW = (u16*)(ws + 48 * MiB);
  u16*   AO     = QKVRAW;
  u16*   A1     = (u16*)(ws + 48 * MiB);
  u16*   QB     = (u16*)(ws + 112 * MiB);
  u16*   KB     = (u16*)(ws + 128 * MiB);
  u16*   VT     = (u16*)(ws + 129 * MiB);
  float* X2     = (float*)(ws + 112 * MiB);
  u16*   Hbf    = (u16*)(ws + 144 * MiB);
  float* COS    = (float*)(ws + 160 * MiB);
  float* SIN    = (float*)(ws + 160 * MiB + 512 * 1024);

  auto cvt = [&](const float* src, u16* dst, size_t n) {
    int n4 = (int)(n / 4);
    cvt_bf16_kernel<<<(n4 + 255) / 256, 256, 0, stream>>>(src, dst, n4);
  };

  rope_table_kernel<<<(NS * 64 + 255) / 256, 256, 0, stream>>>(COS, SIN);

  // h = rmsnorm(x, wn1)
  rmsnorm_kernel<<<NBS, 256, 0, stream>>>(x, wn1, Hbf);

  // qkv_raw = h @ [qw; kvw]^T   (fused, N=2304)
  cvt(qw, R_W, (size_t)ND * ND);
  cvt(kvw, R_W + (size_t)ND * ND, (size_t)256 * ND);
  gemm3_kernel<0><<<dim3(NQKV / 128, NBS / 128), 256, 0, stream>>>(
      Hbf, R_W, (void*)QKVRAW, nullptr, NBS, NQKV, ND);

  // rope
  rope_q_kernel<<<(NB * NS * NH * 64) / 256, 256, 0, stream>>>(QKVRAW, COS, SIN, QB);
  rope_kv_kernel<<<(NB * NS * 64) / 256, 256, 0, stream>>>(QKVRAW, COS, SIN, KB, VT);

  // attention -> AO
  attn_kernel<<<dim3(NS / 64, NB * NH), 256, 0, stream>>>(QB, KB, VT, AO);

  // x2 = x + ao @ ow^T
  cvt(ow, R_W, (size_t)ND * ND);
  gemm3_kernel<1><<<dim3(ND / 128, NBS / 128), 256, 0, stream>>>(
      AO, R_W, (void*)X2, (const void*)x, NBS, ND, ND);

  // h2 = rmsnorm(x2, wn2)
  rmsnorm_kernel<<<NBS, 256, 0, stream>>>(X2, wn2, Hbf);

  // a1 = h2 @ w1^T
  cvt(w1, R_W, (size_t)NFF * ND);
  gemm3_kernel<0><<<dim3(NFF / 128, NBS / 128), 256, 0, stream>>>(
      Hbf, R_W, (void*)A1, nullptr, NBS, NFF, ND);
  // g = silu(a1) * (h2 @ w2^T)  (in-place over A1)
  cvt(w2, R_W, (size_t)NFF * ND);
  gemm3_kernel<2><<<dim3(NFF / 128, NBS / 128), 256, 0, stream>>>(
      Hbf, R_W, (void*)A1, (const void*)A1, NBS, NFF, ND);

  // out = x2 + g @ w3^T
  cvt(w3, R_W, (size_t)ND * NFF);
  gemm3_kernel<1><<<dim3(ND / 128, NBS / 128), 256, 0, stream>>>(
      A1, R_W, (void*)out, (const void*)X2, NBS, ND, NFF);
}

// Round 14
// 875.091 us; speedup vs baseline: 1.3418x; 1.1539x over previous
//
#include <hip/hip_runtime.h>
#include <stdint.h>

#define NB 2
#define NS 2048
#define ND 2048
#define NH 16
#define NHD 128
#define NFF 8192
#define NBS (NB*NS)   // 4096 rows
#define NQKV 2304     // 2048 q + 256 kv

typedef unsigned short u16;
typedef __attribute__((ext_vector_type(8))) short bf16x8;   // 8 bf16 = 4 VGPRs
typedef __attribute__((ext_vector_type(4))) unsigned short u16x4;
typedef __attribute__((ext_vector_type(4))) float f32x4;

__device__ __forceinline__ u16 f2bf(float f) {
  union { float f; unsigned u; } v; v.f = f;
  unsigned r = v.u + 0x7fffu + ((v.u >> 16) & 1u);   // RNE
  return (u16)(r >> 16);
}
__device__ __forceinline__ float bf2f(u16 h) {
  union { unsigned u; float f; } v; v.u = ((unsigned)h) << 16;
  return v.f;
}
__device__ __forceinline__ void async_cp16(const void* g, void* l) {
  __builtin_amdgcn_global_load_lds((const __attribute__((address_space(1))) void*)g,
                                   (__attribute__((address_space(3))) void*)l, 16, 0, 0);
}

// ---------------- fp32 -> bf16 ----------------
__global__ void cvt_bf16_kernel(const float* __restrict__ in, u16* __restrict__ out, int n4) {
  int i = blockIdx.x * blockDim.x + threadIdx.x;
  if (i >= n4) return;
  float4 v = reinterpret_cast<const float4*>(in)[i];
  u16x4 o; o.x = f2bf(v.x); o.y = f2bf(v.y); o.z = f2bf(v.z); o.w = f2bf(v.w);
  reinterpret_cast<u16x4*>(out)[i] = o;
}

// ---------------- RMSNorm (fp32 in -> bf16 out), one block per row ----------------
__global__ __launch_bounds__(256) void rmsnorm_kernel(const float* __restrict__ x,
                                                      const float* __restrict__ w,
                                                      u16* __restrict__ out) {
  const int row = blockIdx.x, tid = threadIdx.x;
  const float* xr = x + (size_t)row * ND;
  float4 a = *reinterpret_cast<const float4*>(xr + tid * 8);
  float4 b = *reinterpret_cast<const float4*>(xr + tid * 8 + 4);
  float ss = a.x*a.x + a.y*a.y + a.z*a.z + a.w*a.w
           + b.x*b.x + b.y*b.y + b.z*b.z + b.w*b.w;
#pragma unroll
  for (int off = 32; off > 0; off >>= 1) ss += __shfl_down(ss, off);
  __shared__ float red[4];
  __shared__ float rinv_s;
  if ((tid & 63) == 0) red[tid >> 6] = ss;
  __syncthreads();
  if (tid == 0) rinv_s = rsqrtf((red[0] + red[1] + red[2] + red[3]) * (1.0f / ND) + 1e-6f);
  __syncthreads();
  const float rinv = rinv_s;
  const float* wr = w + tid * 8;
  u16* orow = out + (size_t)row * ND + tid * 8;
  float vs[8] = {a.x, a.y, a.z, a.w, b.x, b.y, b.z, b.w};
#pragma unroll
  for (int j = 0; j < 8; ++j) orow[j] = f2bf(vs[j] * rinv * wr[j]);
}

// ---------------- RoPE cos/sin table [S][64] ----------------
__global__ void rope_table_kernel(float* __restrict__ cosT, float* __restrict__ sinT) {
  int i = blockIdx.x * blockDim.x + threadIdx.x;
  if (i >= NS * 64) return;
  int s = i >> 6, d = i & 63;
  float freq = expf(-(float)d * (9.210340371976184f / 64.0f));  // 10000^(-d/64)
  float ang = (float)s * freq;
  cosT[i] = cosf(ang);
  sinT[i] = sinf(ang);
}

// ---- RoPE for Q: qkvraw [B,S,2304] bf16 -> [B*H, S, HD] bf16, pre-scaled 1/sqrt(HD) ----
__global__ void rope_q_kernel(const u16* __restrict__ qkvraw, const float* __restrict__ cosT,
                              const float* __restrict__ sinT, u16* __restrict__ qout) {
  int i = blockIdx.x * blockDim.x + threadIdx.x;
  if (i >= NB * NS * NH * 64) return;
  int d = i & 63, h = (i >> 6) & 15, s = (i >> 10) & (NS - 1), b = i >> 21;
  size_t rrow = ((size_t)(b * NS + s)) * NQKV + h * NHD;
  float t1 = bf2f(qkvraw[rrow + d]);
  float t2 = bf2f(qkvraw[rrow + d + 64]);
  float c = cosT[(s << 6) + d], sn = sinT[(s << 6) + d];
  const float scale = 0.08838834764831845f;  // 1/sqrt(128)
  size_t orow = (((size_t)(b * NH + h)) * NS + s) * NHD;
  qout[orow + d]      = f2bf((t1 * c - t2 * sn) * scale);
  qout[orow + d + 64] = f2bf((t2 * c + t1 * sn) * scale);
}

// ---- RoPE for K + transpose-copy V: qkvraw[...,2048+] -> k [B,S,HD], vt [B,128,S] ----
__global__ void rope_kv_kernel(const u16* __restrict__ qkvraw, const float* __restrict__ cosT,
                               const float* __restrict__ sinT, u16* __restrict__ kout,
                               u16* __restrict__ vtout) {
  int i = blockIdx.x * blockDim.x + threadIdx.x;
  if (i >= NB * NS * 64) return;
  int d = i & 63, s = (i >> 6) & (NS - 1), b = i >> 17;
  size_t rrow = ((size_t)(b * NS + s)) * NQKV + ND;
  float t1 = bf2f(qkvraw[rrow + d]);
  float t2 = bf2f(qkvraw[rrow + d + 64]);
  float c = cosT[(s << 6) + d], sn = sinT[(s << 6) + d];
  size_t orow = ((size_t)(b * NS + s)) * NHD;
  kout[orow + d]      = f2bf(t1 * c - t2 * sn);
  kout[orow + d + 64] = f2bf(t2 * c + t1 * sn);
  vtout[((size_t)(b * 128 + d)) * NS + s]      = qkvraw[rrow + 128 + d];
  vtout[((size_t)(b * 128 + d + 64)) * NS + s] = qkvraw[rrow + 128 + d + 64];
}

// ---------------- GEMM v9 (m97-structure + swizzle): C = A[M,K] @ W[N,K]^T (bf16) ----------------
// 128x128 tile, BK=64, 4 waves (2x2), 256 threads. SINGLE-buffered 32KB LDS ->
// multiple blocks/CU resident; cross-BLOCK overlap hides the per-tile barrier drain.
// T2 swizzle (pre-swizzled global source, linear LDS dest, swizzled reads) -> 0 conflicts.
template <int EPI>
__global__ __launch_bounds__(256) void gemm3_kernel(const u16* __restrict__ A,
                                                    const u16* __restrict__ W,
                                                    void* Out, const void* Aux,
                                                    int M, int N, int K) {
  __shared__ __align__(16) char As[128 * 128];   // 128 rows x 128B
  __shared__ __align__(16) char Bs[128 * 128];
  const int tid = threadIdx.x, wave = tid >> 6, lane = tid & 63;
  const int lm = lane & 15, lg = lane >> 4;

  int bx, by;
  {
    const int gx = gridDim.x;
    if ((gx & 7) == 0) {
      const int id = blockIdx.y * gx + blockIdx.x;
      const int xcd = id & 7, rank = id >> 3;
      const int cw = gx >> 3;
      bx = xcd * cw + rank % cw;
      by = rank / cw;
    } else { bx = blockIdx.x; by = blockIdx.y; }
  }
  const int m0 = by * 128, n0 = bx * 128;
  const int wr = wave >> 1, wc = wave & 1;

  f32x4 acc[4][4];
#pragma unroll
  for (int i = 0; i < 4; ++i)
#pragma unroll
    for (int j = 0; j < 4; ++j) acc[i][j] = (f32x4){0.f, 0.f, 0.f, 0.f};

  for (int k0 = 0; k0 < K; k0 += 64) {
#pragma unroll
    for (int p = 0; p < 4; ++p) {
      int X = p * 4096 + tid * 16;            // byte offset within 16KB tile
      int r = X >> 7;                         // row (128B rows)
      int sw = ((X >> 4) ^ (X >> 7)) & 7;     // source 16B group
      async_cp16(A + (size_t)(m0 + r) * K + k0 + sw * 8, As + p * 4096 + wave * 1024);
      async_cp16(W + (size_t)(n0 + r) * K + k0 + sw * 8, Bs + p * 4096 + wave * 1024);
    }
    __syncthreads();
#pragma unroll
    for (int ks = 0; ks < 2; ++ks) {
      bf16x8 a[4], b[4];
#pragma unroll
      for (int i = 0; i < 4; ++i) {
        const int ra = wr * 64 + i * 16 + lm;
        const int sa = (ks * 4 + lg) ^ (ra & 7);
        a[i] = *(const bf16x8*)(As + ra * 128 + sa * 16);
        const int rb = wc * 64 + i * 16 + lm;
        const int sb = (ks * 4 + lg) ^ (rb & 7);
        b[i] = *(const bf16x8*)(Bs + rb * 128 + sb * 16);
      }
#pragma unroll
      for (int i = 0; i < 4; ++i)
#pragma unroll
        for (int j = 0; j < 4; ++j)
          acc[i][j] = __builtin_amdgcn_mfma_f32_16x16x32_bf16(a[i], b[j], acc[i][j], 0, 0, 0);
    }
    __syncthreads();
  }

#pragma unroll
  for (int i = 0; i < 4; ++i) {
    const int row_b = m0 + wr * 64 + i * 16 + lg * 4;
#pragma unroll
    for (int j = 0; j < 4; ++j) {
      const int col = n0 + wc * 64 + j * 16 + lm;
#pragma unroll
      for (int r = 0; r < 4; ++r) {
        size_t idx = (size_t)(row_b + r) * N + col;
        float v = acc[i][j][r];
        if constexpr (EPI == 0) {
          ((u16*)Out)[idx] = f2bf(v);
        } else if constexpr (EPI == 1) {
          ((float*)Out)[idx] = v + ((const float*)Aux)[idx];
        } else {
          float a1 = bf2f(((const u16*)Aux)[idx]);
          float s = a1 / (1.0f + expf(-a1));   // silu
          ((u16*)Out)[idx] = f2bf(s * v);
        }
      }
    }
  }
}

// ---------------- Flash attention v4: QBLK=128, 8 waves, staged K+V ----------------
// grid (S/128, B*H), 512 threads = 8 waves; wave = 16 q rows; KV tiles of 64.
// Both K and V^T staged via global_load_lds (swizzled source, conflict-free reads);
// one staging+barrier pair feeds 256 MFMAs (2x the r11 ratio). LDS 50KB -> 3 blocks/CU.
__global__ __launch_bounds__(512) void attn_kernel(const u16* __restrict__ q,
                                                   const u16* __restrict__ kg,
                                                   const u16* __restrict__ vt,
                                                   u16* __restrict__ out) {
  __shared__ __align__(16) u16 Klds[64 * 128];    // 16KB [kv][slot swizzled]
  __shared__ __align__(16) u16 Vlds[128 * 64];    // 16KB [d][kv-slot swizzled]
  __shared__ __align__(16) u16 Plds[8][16 * 72];  // 18KB wave-private
  const int tid = threadIdx.x, wave = tid >> 6, lane = tid & 63;
  const int qt = (gridDim.x - 1) - blockIdx.x;    // heavy blocks first
  const int q0 = qt * 128;
  const int bh = blockIdx.y, b = bh >> 4, h = bh & 15;
  const float slope = exp2f(-0.5f * (float)(h + 1));
  const int lm = lane & 15, lg = lane >> 4;
  const int crow = lg * 4;

  // Q A-fragments (q pre-scaled by 1/sqrt(HD))
  bf16x8 qf[4];
  {
    const int qrow = q0 + wave * 16 + lm;
    const u16* qbase = q + ((size_t)bh * NS + qrow) * NHD + lg * 8;
#pragma unroll
    for (int kc = 0; kc < 4; ++kc) qf[kc] = *(const bf16x8*)(qbase + kc * 32);
  }

  float Mr[4], Lr[4];
  f32x4 O[8];
#pragma unroll
  for (int r = 0; r < 4; ++r) { Mr[r] = -__builtin_inff(); Lr[r] = 0.f; }
#pragma unroll
  for (int t = 0; t < 8; ++t) O[t] = (f32x4){0.f, 0.f, 0.f, 0.f};

  u16* pw = Plds[wave];

  const int ntiles = 2 * qt + 2;
  for (int t0 = 0; t0 < ntiles; ++t0) {
    const int kv0 = t0 * 64;
    __syncthreads();   // prior-iter LDS reads done before overwrite
    // stage K tile: 64 rows x 256B; 512 threads x 2 x 16B
#pragma unroll
    for (int p = 0; p < 2; ++p) {
      int X = p * 8192 + tid * 16;
      int kv = X >> 8;                 // 256B rows
      int sl = (X >> 4) & 15;
      const u16* src = kg + ((size_t)b * NS + kv0 + kv) * NHD + ((sl ^ (kv & 7)) * 8);
      async_cp16(src, (char*)Klds + p * 8192 + wave * 1024);
    }
    // stage V^T tile: 128 rows x 128B; 512 threads x 2 x 16B
#pragma unroll
    for (int p = 0; p < 2; ++p) {
      int X = p * 8192 + tid * 16;
      int d = X >> 7;                  // 128B rows
      int sl = (X >> 4) & 7;
      const u16* src = vt + ((size_t)b * 128 + d) * NS + kv0 + ((sl ^ (d & 7)) * 8);
      async_cp16(src, (char*)Vlds + p * 8192 + wave * 1024);
    }
    __syncthreads();   // staged data visible

    // ---- QK^T from LDS ----
    f32x4 sc[4];
#pragma unroll
    for (int sub = 0; sub < 4; ++sub) sc[sub] = (f32x4){0.f, 0.f, 0.f, 0.f};
#pragma unroll
    for (int sub = 0; sub < 4; ++sub) {
      const int kv = sub * 16 + lm;
#pragma unroll
      for (int kc = 0; kc < 4; ++kc) {
        const int slot = (kc * 4 + lg) ^ (kv & 7);
        bf16x8 kf = *(const bf16x8*)((const char*)Klds + kv * 256 + slot * 16);
        sc[sub] = __builtin_amdgcn_mfma_f32_16x16x32_bf16(qf[kc], kf, sc[sub], 0, 0, 0);
      }
    }

    // ---- ALiBi + causal + online softmax ----
    float esc[4], pp[4][4];
#pragma unroll
    for (int r = 0; r < 4; ++r) {
      const int sq = q0 + wave * 16 + crow + r;
      float v[4];
#pragma unroll
      for (int sub = 0; sub < 4; ++sub) {
        const int kc_ = kv0 + sub * 16 + lm;
        v[sub] = (kc_ <= sq) ? sc[sub][r] - slope * (float)(sq - kc_) : -1e9f;
      }
      float mx = fmaxf(fmaxf(v[0], v[1]), fmaxf(v[2], v[3]));
      mx = fmaxf(mx, __shfl_xor(mx, 1));
      mx = fmaxf(mx, __shfl_xor(mx, 2));
      mx = fmaxf(mx, __shfl_xor(mx, 4));
      mx = fmaxf(mx, __shfl_xor(mx, 8));
      const float newM = fmaxf(Mr[r], mx);
      esc[r] = __expf(Mr[r] - newM);
      float rs = 0.f;
#pragma unroll
      for (int sub = 0; sub < 4; ++sub) { pp[sub][r] = __expf(v[sub] - newM); rs += pp[sub][r]; }
      rs += __shfl_xor(rs, 1);
      rs += __shfl_xor(rs, 2);
      rs += __shfl_xor(rs, 4);
      rs += __shfl_xor(rs, 8);
      Lr[r] = Lr[r] * esc[r] + rs;
      Mr[r] = newM;
    }
#pragma unroll
    for (int t = 0; t < 8; ++t) {
      O[t][0] *= esc[0]; O[t][1] *= esc[1]; O[t][2] *= esc[2]; O[t][3] *= esc[3];
    }

    // ---- P -> wave-private LDS (padded rows); no cross-wave barrier needed ----
#pragma unroll
    for (int sub = 0; sub < 4; ++sub)
#pragma unroll
      for (int r = 0; r < 4; ++r)
        pw[(crow + r) * 72 + sub * 16 + lm] = f2bf(pp[sub][r]);

    bf16x8 pa0 = *(const bf16x8*)&pw[lm * 72 + lg * 8];
    bf16x8 pa1 = *(const bf16x8*)&pw[lm * 72 + 32 + lg * 8];

    // ---- PV from LDS ----
#pragma unroll
    for (int dt = 0; dt < 8; ++dt) {
      const int d = dt * 16 + lm;
      const int s0 = (lg) ^ (d & 7);
      const int s1 = (4 + lg) ^ (d & 7);
      bf16x8 vf0 = *(const bf16x8*)((const char*)Vlds + d * 128 + s0 * 16);
      bf16x8 vf1 = *(const bf16x8*)((const char*)Vlds + d * 128 + s1 * 16);
      O[dt] = __builtin_amdgcn_mfma_f32_16x16x32_bf16(pa0, vf0, O[dt], 0, 0, 0);
      O[dt] = __builtin_amdgcn_mfma_f32_16x16x32_bf16(pa1, vf1, O[dt], 0, 0, 0);
    }
  }

  // ---- normalize + store [B,S,H*HD] ----
#pragma unroll
  for (int dt = 0; dt < 8; ++dt) {
#pragma unroll
    for (int r = 0; r < 4; ++r) {
      const int sq = q0 + wave * 16 + crow + r;
      out[((size_t)b * NS + sq) * ND + h * NHD + dt * 16 + lm] = f2bf(O[dt][r] / Lr[r]);
    }
  }
}

// ---------------- host ----------------
extern "C" void kernel_launch(void* const* d_in, const int* in_sizes, int n_in,
                              void* d_out, int out_size, void* d_ws, size_t ws_size,
                              hipStream_t stream) {
  const float* x   = (const float*)d_in[0];
  const float* wn1 = (const float*)d_in[2];
  const float* wn2 = (const float*)d_in[3];
  const float* qw  = (const float*)d_in[4];
  const float* kvw = (const float*)d_in[5];
  const float* ow  = (const float*)d_in[6];
  const float* w1  = (const float*)d_in[7];
  const float* w2  = (const float*)d_in[8];
  const float* w3  = (const float*)d_in[9];
  float* out = (float*)d_out;

  const size_t MiB = 1024 * 1024;
  const size_t NEED = 161 * MiB;
  if (ws_size < NEED) return;

  char* ws = (char*)d_ws;
  u16*   R_W    = (u16*)(ws);
  u16*   QKVRAW = (u16*)(ws + 48 * MiB);
  u16*   AO     = QKVRAW;
  u16*   A1     = (u16*)(ws + 48 * MiB);
  u16*   QB     = (u16*)(ws + 112 * MiB);
  u16*   KB     = (u16*)(ws + 128 * MiB);
  u16*   VT     = (u16*)(ws + 129 * MiB);
  float* X2     = (float*)(ws + 112 * MiB);
  u16*   Hbf    = (u16*)(ws + 144 * MiB);
  float* COS    = (float*)(ws + 160 * MiB);
  float* SIN    = (float*)(ws + 160 * MiB + 512 * 1024);

  auto cvt = [&](const float* src, u16* dst, size_t n) {
    int n4 = (int)(n / 4);
    cvt_bf16_kernel<<<(n4 + 255) / 256, 256, 0, stream>>>(src, dst, n4);
  };

  rope_table_kernel<<<(NS * 64 + 255) / 256, 256, 0, stream>>>(COS, SIN);

  // h = rmsnorm(x, wn1)
  rmsnorm_kernel<<<NBS, 256, 0, stream>>>(x, wn1, Hbf);

  // qkv_raw = h @ [qw; kvw]^T   (fused, N=2304)
  cvt(qw, R_W, (size_t)ND * ND);
  cvt(kvw, R_W + (size_t)ND * ND, (size_t)256 * ND);
  gemm3_kernel<0><<<dim3(NQKV / 128, NBS / 128), 256, 0, stream>>>(
      Hbf, R_W, (void*)QKVRAW, nullptr, NBS, NQKV, ND);

  // rope
  rope_q_kernel<<<(NB * NS * NH * 64) / 256, 256, 0, stream>>>(QKVRAW, COS, SIN, QB);
  rope_kv_kernel<<<(NB * NS * 64) / 256, 256, 0, stream>>>(QKVRAW, COS, SIN, KB, VT);

  // attention -> AO   (QBLK=128, 8 waves)
  attn_kernel<<<dim3(NS / 128, NB * NH), 512, 0, stream>>>(QB, KB, VT, AO);

  // x2 = x + ao @ ow^T
  cvt(ow, R_W, (size_t)ND * ND);
  gemm3_kernel<1><<<dim3(ND / 128, NBS / 128), 256, 0, stream>>>(
      AO, R_W, (void*)X2, (const void*)x, NBS, ND, ND);

  // h2 = rmsnorm(x2, wn2)
  rmsnorm_kernel<<<NBS, 256, 0, stream>>>(X2, wn2, Hbf);

  // a1 = h2 @ w1^T
  cvt(w1, R_W, (size_t)NFF * ND);
  gemm3_kernel<0><<<dim3(NFF / 128, NBS / 128), 256, 0, stream>>>(
      Hbf, R_W, (void*)A1, nullptr, NBS, NFF, ND);
  // g = silu(a1) * (h2 @ w2^T)  (in-place over A1)
  cvt(w2, R_W, (size_t)NFF * ND);
  gemm3_kernel<2><<<dim3(NFF / 128, NBS / 128), 256, 0, stream>>>(
      Hbf, R_W, (void*)A1, (const void*)A1, NBS, NFF, ND);

  // out = x2 + g @ w3^T
  cvt(w3, R_W, (size_t)ND * NFF);
  gemm3_kernel<1><<<dim3(ND / 128, NBS / 128), 256, 0, stream>>>(
      A1, R_W, (void*)out, (const void*)X2, NBS, ND, NFF);
}